// Round 4
// baseline (981.682 us; speedup 1.0000x reference)
//
#include <hip/hip_runtime.h>

// Problem constants (match reference setup_inputs)
constexpr int T = 8;
constexpr int R = 200000;
constexpr int D = 128;
constexpr int B = 2048;
constexpr int NUM_BAGS = T * B;  // 16384
constexpr int N_TOTAL = 524288;  // T * B * L
constexpr int SHIFT = 100003;    // row shift for the probe pass (< R)

typedef int   iv4 __attribute__((ext_vector_type(4)));
typedef float fv2 __attribute__((ext_vector_type(2)));

// ROUND-4 PROBE KERNEL (corrected from round 3).
// Pass 1 = the real round-0 gather+pool. Pass 2 = an equal-size gather of
// DISTINCT rows (index shifted by +100003 mod R): uniform-random, in-bounds,
// same table, but disjoint from pass 1's rows -> pass 2's misses are COLD,
// unlike round 3 where identical addresses made pass 2 an L2-hit replay.
// Pass 2's accumulators fold into the output with runtime weight 0.0f
// (offsets[NUM_BAGS]==N_TOTAL is data the compiler can't fold), so the
// output is bit-identical. dur(round4) - dur(round2) == marginal cost of
// one full COLD gather pass == the controllable budget in the window.
__global__ __launch_bounds__(256)
void qembag_kernel(const int* __restrict__ indices,
                   const int* __restrict__ offsets,
                   const int* __restrict__ qweights,
                   const float* __restrict__ scale_shift,
                   float* __restrict__ out) {
    const int wave_id = (int)((blockIdx.x * blockDim.x + threadIdx.x) >> 6);
    if (wave_id >= NUM_BAGS) return;
    const int lane = (int)(threadIdx.x & 63);
    const int half = lane >> 5;   // which lookup of an interleaved pair
    const int sub  = lane & 31;   // 16B chunk within the 512B row

    const int t     = wave_id >> 11;      // bag / B   (B = 2048)
    const int batch = wave_id & (B - 1);  // bag % B

    // Runtime zero (CSR terminator is data, not a compile-time constant)
    const int zoff = (offsets[NUM_BAGS] == N_TOTAL) ? 0 : 1;

    const int start = offsets[wave_id];
    const int end   = offsets[wave_id + 1];
    const int len   = end - start;
    const int C     = len >> 4;           // full chunks of 16 lookups

    const long tbase = (long)t * R;
    const iv4* qw4 = (const iv4*)qweights;    // row r -> qw4[r*32 + sub]
    const fv2* ss2 = (const fv2*)scale_shift; // row r -> ss2[r]

    float acc0 = 0.f, acc1 = 0.f, acc2 = 0.f, acc3 = 0.f;
    float sshift = 0.f;

    // ---------------- PASS 1 (real) ----------------
    {
        int idxb[8];
        if (C > 0) {
#pragma unroll
            for (int k = 0; k < 8; ++k) idxb[k] = indices[start + half + 2 * k];
        }
        for (int c = 0; c < C; ++c) {
            iv4 q[8];
            fv2 s[8];
#pragma unroll
            for (int k = 0; k < 8; ++k) {
                const long r = tbase + idxb[k];
                q[k] = qw4[r * 32 + sub];
                s[k] = ss2[r];
            }
            if (c + 1 < C) {
                const int nbase = start + ((c + 1) << 4) + half;
#pragma unroll
                for (int k = 0; k < 8; ++k) idxb[k] = indices[nbase + 2 * k];
            }
#pragma unroll
            for (int k = 0; k < 8; ++k) {
                const float sc = s[k].x;
                sshift += s[k].y;
                acc0 = fmaf((float)q[k].x, sc, acc0);
                acc1 = fmaf((float)q[k].y, sc, acc1);
                acc2 = fmaf((float)q[k].z, sc, acc2);
                acc3 = fmaf((float)q[k].w, sc, acc3);
            }
        }
        for (int j = start + (C << 4) + half; j < end; j += 2) {
            const long r = tbase + indices[j];
            const iv4 q = qw4[r * 32 + sub];
            const fv2 ss = ss2[r];
            sshift += ss.y;
            acc0 = fmaf((float)q.x, ss.x, acc0);
            acc1 = fmaf((float)q.y, ss.x, acc1);
            acc2 = fmaf((float)q.z, ss.x, acc2);
            acc3 = fmaf((float)q.w, ss.x, acc3);
        }
    }

    // -------- PASS 2 (probe: equal-size gather of DISTINCT cold rows) -------
    float b0 = 0.f, b1 = 0.f, b2 = 0.f, b3 = 0.f, bsh = 0.f;
    {
        int idxb[8];
        if (C > 0) {
#pragma unroll
            for (int k = 0; k < 8; ++k) {
                int r2 = indices[start + half + 2 * k] + SHIFT;
                if (r2 >= R) r2 -= R;
                idxb[k] = r2;
            }
        }
        for (int c = 0; c < C; ++c) {
            iv4 q[8];
            fv2 s[8];
#pragma unroll
            for (int k = 0; k < 8; ++k) {
                const long r = tbase + idxb[k];
                q[k] = qw4[r * 32 + sub];
                s[k] = ss2[r];
            }
            if (c + 1 < C) {
                const int nbase = start + ((c + 1) << 4) + half;
#pragma unroll
                for (int k = 0; k < 8; ++k) {
                    int r2 = indices[nbase + 2 * k] + SHIFT;
                    if (r2 >= R) r2 -= R;
                    idxb[k] = r2;
                }
            }
#pragma unroll
            for (int k = 0; k < 8; ++k) {
                const float sc = s[k].x;
                bsh += s[k].y;
                b0 = fmaf((float)q[k].x, sc, b0);
                b1 = fmaf((float)q[k].y, sc, b1);
                b2 = fmaf((float)q[k].z, sc, b2);
                b3 = fmaf((float)q[k].w, sc, b3);
            }
        }
        for (int j = start + (C << 4) + half; j < end; j += 2) {
            int r2 = indices[j] + SHIFT;
            if (r2 >= R) r2 -= R;
            const long r = tbase + r2;
            const iv4 q = qw4[r * 32 + sub];
            const fv2 ss = ss2[r];
            bsh += ss.y;
            b0 = fmaf((float)q.x, ss.x, b0);
            b1 = fmaf((float)q.y, ss.x, b1);
            b2 = fmaf((float)q.z, ss.x, b2);
            b3 = fmaf((float)q.w, ss.x, b3);
        }
    }

    // Fold probe pass with runtime weight 0.0f: output is bit-identical.
    const float zf = (float)zoff;   // 0.0f at runtime
    acc0 = fmaf(zf, b0, acc0);
    acc1 = fmaf(zf, b1, acc1);
    acc2 = fmaf(zf, b2, acc2);
    acc3 = fmaf(zf, b3, acc3);
    sshift = fmaf(zf, bsh, sshift);

    acc0 += sshift; acc1 += sshift; acc2 += sshift; acc3 += sshift;

    // Fold the two half-wave partial sums: lane s += lane s+32
    acc0 += __shfl_down(acc0, 32);
    acc1 += __shfl_down(acc1, 32);
    acc2 += __shfl_down(acc2, 32);
    acc3 += __shfl_down(acc3, 32);

    if (half == 0) {
        float4 v = make_float4(acc0, acc1, acc2, acc3);
        ((float4*)(out + (long)batch * (T * D) + t * D))[sub] = v;
    }
}

extern "C" void kernel_launch(void* const* d_in, const int* in_sizes, int n_in,
                              void* d_out, int out_size, void* d_ws, size_t ws_size,
                              hipStream_t stream) {
    const int*   indices     = (const int*)d_in[0];
    const int*   offsets     = (const int*)d_in[1];
    const int*   qweights    = (const int*)d_in[2];
    const float* scale_shift = (const float*)d_in[3];
    float*       out         = (float*)d_out;

    const int blocks = NUM_BAGS / 4;  // 4 waves/block, one wave per bag
    qembag_kernel<<<blocks, 256, 0, stream>>>(indices, offsets, qweights,
                                              scale_shift, out);
}

// Round 5
// 927.589 us; speedup vs baseline: 1.0583x; 1.0583x over previous
//
#include <hip/hip_runtime.h>

// Problem constants (match reference setup_inputs)
constexpr int T = 8;
constexpr int R = 200000;
constexpr int D = 128;
constexpr int B = 2048;
constexpr int NUM_BAGS = T * B;  // 16384

typedef int   iv4 __attribute__((ext_vector_type(4)));
typedef float fv2 __attribute__((ext_vector_type(2)));

// FINAL (restored round-0 best, 926.5us). Session evidence for why this is
// the roofline:
//  - R4 probe: one EXTRA full cold gather pass (268MB of 512B random reads)
//    costs +49us -> effective ~5.5 TB/s, within ~15% of the 6.3 TB/s
//    streaming ceiling. The gather phase is BW-roofline-bound at ~50-60us.
//  - The ~930us metric window is dominated by fixed harness work (520us
//    3.2GB workspace re-poison fill + input restores), not the kernel.
//  - R1: int8-compacted table (4x fewer gathered bytes) -> no gain on the
//    pool phase, and the compaction passes cost +90us. Net loss.
//  - R2: 2-deep explicit software pipeline -> neutral (not latency-bound).
//  - R3: issue+cache-hit cost of a full gather phase = +17us (VALU trivial).
//
// One 64-lane wave per bag; two half-waves own alternating lookups.
// Lane sub in a half-wave loads 16B at dim 4*sub -> each row read is one
// coalesced 32-lane x 16B = 512B transaction. 8-deep gather batching per
// half (16 rows in flight per wave); next chunk's indices prefetched
// behind the gathers; shift pooled separately and applied once.
__global__ __launch_bounds__(256)
void qembag_kernel(const int* __restrict__ indices,
                   const int* __restrict__ offsets,
                   const int* __restrict__ qweights,
                   const float* __restrict__ scale_shift,
                   float* __restrict__ out) {
    const int wave_id = (int)((blockIdx.x * blockDim.x + threadIdx.x) >> 6);
    if (wave_id >= NUM_BAGS) return;
    const int lane = (int)(threadIdx.x & 63);
    const int half = lane >> 5;   // which lookup of an interleaved pair
    const int sub  = lane & 31;   // 16B chunk within the 512B row

    const int bag   = wave_id;
    const int t     = bag >> 11;      // bag / B   (B = 2048)
    const int batch = bag & (B - 1);  // bag % B

    const int start = offsets[bag];
    const int end   = offsets[bag + 1];
    const int len   = end - start;
    const int C     = len >> 4;       // full chunks of 16 lookups (8 per half)

    float acc0 = 0.f, acc1 = 0.f, acc2 = 0.f, acc3 = 0.f;
    float sshift = 0.f;               // pooled shift, added to all dims at end

    const long tbase = (long)t * R;
    const iv4* qw4 = (const iv4*)qweights;       // row r -> qw4[r*32 + sub]
    const fv2* ss2 = (const fv2*)scale_shift;    // row r -> ss2[r]

    // prologue: preload chunk 0's indices
    int idxb[8];
    if (C > 0) {
#pragma unroll
        for (int k = 0; k < 8; ++k) idxb[k] = indices[start + half + 2 * k];
    }

    for (int c = 0; c < C; ++c) {
        // 1) issue all 16 gathers (8 rows + 8 scale/shift) back-to-back
        iv4 q[8];
        fv2 s[8];
#pragma unroll
        for (int k = 0; k < 8; ++k) {
            const long r = tbase + idxb[k];
            q[k] = __builtin_nontemporal_load(&qw4[r * 32 + sub]);
            s[k] = ss2[r];
        }

        // 2) prefetch next chunk's indices while gathers are in flight
        if (c + 1 < C) {
            const int nbase = start + ((c + 1) << 4) + half;
#pragma unroll
            for (int k = 0; k < 8; ++k) idxb[k] = indices[nbase + 2 * k];
        }

        // 3) accumulate (shift hoisted: pooled separately, added once)
#pragma unroll
        for (int k = 0; k < 8; ++k) {
            const float sc = s[k].x;
            sshift += s[k].y;
            acc0 = fmaf((float)q[k].x, sc, acc0);
            acc1 = fmaf((float)q[k].y, sc, acc1);
            acc2 = fmaf((float)q[k].z, sc, acc2);
            acc3 = fmaf((float)q[k].w, sc, acc3);
        }
    }

    // remainder (< 16 lookups), interleaved between halves as before
    for (int j = start + (C << 4) + half; j < end; j += 2) {
        const long r = tbase + indices[j];
        const iv4 q = __builtin_nontemporal_load(&qw4[r * 32 + sub]);
        const fv2 ss = ss2[r];
        sshift += ss.y;
        acc0 = fmaf((float)q.x, ss.x, acc0);
        acc1 = fmaf((float)q.y, ss.x, acc1);
        acc2 = fmaf((float)q.z, ss.x, acc2);
        acc3 = fmaf((float)q.w, ss.x, acc3);
    }

    acc0 += sshift; acc1 += sshift; acc2 += sshift; acc3 += sshift;

    // Fold the two half-wave partial sums: lane s += lane s+32
    acc0 += __shfl_down(acc0, 32);
    acc1 += __shfl_down(acc1, 32);
    acc2 += __shfl_down(acc2, 32);
    acc3 += __shfl_down(acc3, 32);

    if (half == 0) {
        float4 v = make_float4(acc0, acc1, acc2, acc3);
        ((float4*)(out + (long)batch * (T * D) + t * D))[sub] = v;
    }
}

extern "C" void kernel_launch(void* const* d_in, const int* in_sizes, int n_in,
                              void* d_out, int out_size, void* d_ws, size_t ws_size,
                              hipStream_t stream) {
    const int*   indices     = (const int*)d_in[0];
    const int*   offsets     = (const int*)d_in[1];
    const int*   qweights    = (const int*)d_in[2];
    const float* scale_shift = (const float*)d_in[3];
    float*       out         = (float*)d_out;

    // 4 waves per 256-thread block, one wave per bag
    const int blocks = NUM_BAGS / 4;  // 4096
    qembag_kernel<<<blocks, 256, 0, stream>>>(indices, offsets, qweights,
                                              scale_shift, out);
}